// Round 1
// baseline (914.986 us; speedup 1.0000x reference)
//
#include <hip/hip_runtime.h>
#include <cstdint>
#include <cstddef>

#define DEV __device__ __forceinline__

typedef __attribute__((ext_vector_type(4))) float  f32x4;
typedef __attribute__((ext_vector_type(4))) float  float4v;
typedef __attribute__((ext_vector_type(8))) short  s16x8;
typedef __attribute__((ext_vector_type(4))) short  s16x4;

static constexpr int BB = 2, SS = 2048, HIDN = 1024, NHH = 16, FFN = 4096, DH = 64;
static constexpr int TWOK = 1024;                  // 2*K
static constexpr float ATT_SCALE = 0.07216878364870322f;  // 1/sqrt(3*DH)

DEV short f2bf(float f) {
  union { float f; uint32_t u; } v; v.f = f;
  uint32_t r = (v.u + 0x7fffu + ((v.u >> 16) & 1u)) >> 16;
  return (short)r;
}
DEV int imin(int a, int b) { return a < b ? a : b; }
DEV int imax(int a, int b) { return a > b ? a : b; }

DEV void gl_lds16(const void* g, void* l) {
  __builtin_amdgcn_global_load_lds((const __attribute__((address_space(1))) void*)g,
                                   (__attribute__((address_space(3))) void*)l, 16, 0, 0);
}

#define MFMA16(a, b, c) __builtin_amdgcn_mfma_f32_16x16x32_bf16((a), (b), (c), 0, 0, 0)

// ---------------------------------------------------------------- transpose+cast
// in fp32 [R][C] -> out bf16 [C][R]
__global__ __launch_bounds__(256) void k_tcast(const float* __restrict__ in,
                                               short* __restrict__ out, int R, int C) {
  __shared__ float t[32][33];
  const int bx = blockIdx.x * 32;   // C
  const int by = blockIdx.y * 32;   // R
  const int tx = threadIdx.x & 31, ty = threadIdx.x >> 5;   // 32 x 8
#pragma unroll
  for (int r = ty; r < 32; r += 8) t[r][tx] = in[(size_t)(by + r) * C + bx + tx];
  __syncthreads();
#pragma unroll
  for (int c = ty; c < 32; c += 8) out[(size_t)(bx + c) * R + by + tx] = f2bf(t[tx][c]);
}

// ---------------------------------------------------------------- plain cast fp32->bf16
__global__ __launch_bounds__(256) void k_cast(const float* __restrict__ in,
                                              short* __restrict__ out, int n4) {
  const int i = blockIdx.x * 256 + threadIdx.x;
  if (i < n4) {
    float4v v = ((const float4v*)in)[i];
    s16x4 o; o[0] = f2bf(v.x); o[1] = f2bf(v.y); o[2] = f2bf(v.z); o[3] = f2bf(v.w);
    ((s16x4*)out)[i] = o;
  }
}

// ---------------------------------------------------------------- layernorm fp32 -> bf16
__global__ __launch_bounds__(256) void k_ln(const float* __restrict__ x,
                                            const float* __restrict__ gw,
                                            const float* __restrict__ bw,
                                            short* __restrict__ out) {
  const int row = blockIdx.x, t = threadIdx.x, lane = t & 63, wv = t >> 6;
  __shared__ float red[8];
  const float4v v = ((const float4v*)(x + (size_t)row * HIDN))[t];
  float s = v.x + v.y + v.z + v.w;
#pragma unroll
  for (int d = 1; d < 64; d <<= 1) s += __shfl_xor(s, d, 64);
  if (lane == 0) red[wv] = s;
  __syncthreads();
  const float mean = (red[0] + red[1] + red[2] + red[3]) * (1.f / 1024.f);
  const float dx = v.x - mean, dy = v.y - mean, dz = v.z - mean, dw = v.w - mean;
  float s2 = dx * dx + dy * dy + dz * dz + dw * dw;
#pragma unroll
  for (int d = 1; d < 64; d <<= 1) s2 += __shfl_xor(s2, d, 64);
  if (lane == 0) red[4 + wv] = s2;
  __syncthreads();
  const float var = (red[4] + red[5] + red[6] + red[7]) * (1.f / 1024.f);
  const float rs = rsqrtf(var + 1e-6f);
  const float4v g4 = ((const float4v*)gw)[t], b4 = ((const float4v*)bw)[t];
  s16x4 o;
  o[0] = f2bf(dx * rs * g4.x + b4.x);
  o[1] = f2bf(dy * rs * g4.y + b4.y);
  o[2] = f2bf(dz * rs * g4.z + b4.z);
  o[3] = f2bf(dw * rs * g4.w + b4.w);
  ((s16x4*)(out + (size_t)row * HIDN))[t] = o;
}

// ---------------------------------------------------------------- GEMM (m97 structure)
// C[M,N] = A[M,K](bf16,row-major) @ Bt[N,K](bf16,row-major)^T + bias
enum { OM_HEADS = 0, OM_VT = 1, OM_POS = 2, OM_GELU = 3, OM_RESID = 4 };

template <int OM>
__global__ __launch_bounds__(256) void k_gemm(const short* __restrict__ A,
                                              const short* __restrict__ Bt,
                                              const float* __restrict__ bias,
                                              const float* __restrict__ resid,
                                              void* __restrict__ out,
                                              int M, int N, int K) {
  __shared__ short As[128 * 32];
  __shared__ short Bs[128 * 32];
  const int tid = threadIdx.x, lane = tid & 63;
  const int wave = tid >> 6;
  const int m0 = blockIdx.y * 128, n0 = blockIdx.x * 128;
  const int wm = (wave >> 1) * 64, wn = (wave & 1) * 64;
  const int lr = lane & 15, lg = lane >> 4;

  f32x4 acc[4][4];
#pragma unroll
  for (int i = 0; i < 4; ++i)
#pragma unroll
    for (int j = 0; j < 4; ++j) acc[i][j] = (f32x4){0.f, 0.f, 0.f, 0.f};

  for (int k0 = 0; k0 < K; k0 += 32) {
#pragma unroll
    for (int c = tid; c < 512; c += 256) {
      const int row = c >> 2, col = (c & 3) * 8;
      gl_lds16(A + (size_t)(m0 + row) * K + k0 + col, (char*)As + c * 16);
      gl_lds16(Bt + (size_t)(n0 + row) * K + k0 + col, (char*)Bs + c * 16);
    }
    __syncthreads();
    s16x8 af[4], bf[4];
#pragma unroll
    for (int fi = 0; fi < 4; ++fi) af[fi] = *(const s16x8*)&As[(wm + fi * 16 + lr) * 32 + lg * 8];
#pragma unroll
    for (int fj = 0; fj < 4; ++fj) bf[fj] = *(const s16x8*)&Bs[(wn + fj * 16 + lr) * 32 + lg * 8];
#pragma unroll
    for (int fi = 0; fi < 4; ++fi)
#pragma unroll
      for (int fj = 0; fj < 4; ++fj) acc[fi][fj] = MFMA16(af[fi], bf[fj], acc[fi][fj]);
    __syncthreads();
  }

#pragma unroll
  for (int fi = 0; fi < 4; ++fi)
#pragma unroll
    for (int fj = 0; fj < 4; ++fj) {
      const int n = n0 + wn + fj * 16 + lr;
      const float bv = bias ? bias[n] : 0.f;
#pragma unroll
      for (int r = 0; r < 4; ++r) {
        const int m = m0 + wm + fi * 16 + lg * 4 + r;
        float v = acc[fi][fj][r] + bv;
        if constexpr (OM == OM_HEADS) {
          const int b = m >> 11, s = m & (SS - 1);
          const int hh = n >> 6, dd = n & 63;
          ((short*)out)[(((size_t)b * NHH + hh) * SS + s) * DH + dd] = f2bf(v);
        } else if constexpr (OM == OM_VT) {
          const int b = m >> 11, s = m & (SS - 1);
          const int hh = n >> 6, dd = n & 63;
          ((short*)out)[(((size_t)b * NHH + hh) * DH + dd) * SS + s] = f2bf(v);
        } else if constexpr (OM == OM_POS) {
          const int hh = n >> 6, dd = n & 63;
          ((short*)out)[((size_t)hh * TWOK + m) * DH + dd] = f2bf(v);
        } else if constexpr (OM == OM_GELU) {
          const float th = tanhf(0.7978845608028654f * (v + 0.044715f * v * v * v));
          ((short*)out)[(size_t)m * N + n] = f2bf(0.5f * v * (1.f + th));
        } else {  // OM_RESID, fp32 out
          ((float*)out)[(size_t)m * N + n] = v + resid[(size_t)m * N + n];
        }
      }
    }
}

// ---------------------------------------------------------------- flash disentangled attention
__global__ __launch_bounds__(256) void k_attn(const short* __restrict__ qh,
                                              const short* __restrict__ kh,
                                              const short* __restrict__ vT,
                                              const short* __restrict__ pk,
                                              const short* __restrict__ pq,
                                              const int* __restrict__ mask,
                                              short* __restrict__ ao) {
  __shared__ short Qs[64 * 64];
  __shared__ short Ks[64 * 64];
  __shared__ short Vs[64 * 64];
  __shared__ short PKs[128 * 64];
  __shared__ short PQs[128 * 64];
  __shared__ float TK[64 * 128];
  __shared__ float TQ[64 * 128];
  __shared__ short Ps[64 * 64];
  __shared__ int msk[64];

  const int tid = threadIdx.x, lane = tid & 63, wv = tid >> 6;
  const int lr = lane & 15, lg = lane >> 4;
  const int band = wv * 16;

  const int bid = blockIdx.x;
  const int itile = bid & 31;
  const int h = (bid >> 5) & (NHH - 1);
  const int b = bid >> 9;
  const int i0 = itile * 64;
  const size_t bhoff = ((size_t)b * NHH + h) * SS * DH;

  {  // stage Q once (contiguous 8KB)
    const char* qt = (const char*)(qh + bhoff + (size_t)i0 * DH);
#pragma unroll
    for (int c = tid; c < 512; c += 256) gl_lds16(qt + c * 16, (char*)Qs + c * 16);
  }

  f32x4 oacc[4];
  float mprev[4], lsum[4];
#pragma unroll
  for (int r = 0; r < 4; ++r) {
    mprev[r] = -1e30f; lsum[r] = 0.f; oacc[r] = (f32x4){0.f, 0.f, 0.f, 0.f};
  }

  for (int jt = 0; jt < SS / 64; ++jt) {
    const int j0 = jt * 64;
    const int d0 = i0 - j0;
    const int rmin = imin(imax(d0 - 63 + 512, 0), 1023);
    const int r2min = imin(imax(-d0 - 63 + 512, 0), 1023);

    {  // stage K, V^T, pos windows, mask
      const char* kt = (const char*)(kh + bhoff + (size_t)j0 * DH);
#pragma unroll
      for (int c = tid; c < 512; c += 256) gl_lds16(kt + c * 16, (char*)Ks + c * 16);
#pragma unroll
      for (int c = tid; c < 512; c += 256) {
        const int d = c >> 3, co = (c & 7) * 8;
        gl_lds16(vT + bhoff + (size_t)d * SS + j0 + co, (char*)Vs + c * 16);
      }
#pragma unroll
      for (int c = tid; c < 1024; c += 256) {
        const int w = c >> 3, co = (c & 7) * 8;
        const int r = imin(rmin + w, 1023);
        gl_lds16(pk + ((size_t)h * TWOK + r) * DH + co, (char*)PKs + c * 16);
      }
#pragma unroll
      for (int c = tid; c < 1024; c += 256) {
        const int w = c >> 3, co = (c & 7) * 8;
        const int r = imin(r2min + w, 1023);
        gl_lds16(pq + ((size_t)h * TWOK + r) * DH + co, (char*)PQs + c * 16);
      }
      if (tid < 64) msk[tid] = mask[(size_t)b * SS + j0 + tid];
    }
    __syncthreads();

    // ---- Phase B: MFMA (c2c + pos windows)
    const s16x8 qa0 = *(const s16x8*)&Qs[(band + lr) * 64 + lg * 8];
    const s16x8 qa1 = *(const s16x8*)&Qs[(band + lr) * 64 + 32 + lg * 8];
    f32x4 sacc[4];
#pragma unroll
    for (int fj = 0; fj < 4; ++fj) {
      f32x4 a = (f32x4){0.f, 0.f, 0.f, 0.f};
      const s16x8 k0f = *(const s16x8*)&Ks[(fj * 16 + lr) * 64 + lg * 8];
      const s16x8 k1f = *(const s16x8*)&Ks[(fj * 16 + lr) * 64 + 32 + lg * 8];
      a = MFMA16(qa0, k0f, a);
      a = MFMA16(qa1, k1f, a);
      sacc[fj] = a;
    }
#pragma unroll
    for (int fw = 0; fw < 8; ++fw) {  // tmpk[i][w] = q_i . pos_k[rmin+w]
      f32x4 t = (f32x4){0.f, 0.f, 0.f, 0.f};
      const s16x8 p0 = *(const s16x8*)&PKs[(fw * 16 + lr) * 64 + lg * 8];
      const s16x8 p1 = *(const s16x8*)&PKs[(fw * 16 + lr) * 64 + 32 + lg * 8];
      t = MFMA16(qa0, p0, t);
      t = MFMA16(qa1, p1, t);
#pragma unroll
      for (int r = 0; r < 4; ++r) TK[(band + lg * 4 + r) * 128 + fw * 16 + lr] = t[r];
    }
    const s16x8 ka0 = *(const s16x8*)&Ks[(band + lr) * 64 + lg * 8];
    const s16x8 ka1 = *(const s16x8*)&Ks[(band + lr) * 64 + 32 + lg * 8];
#pragma unroll
    for (int fw = 0; fw < 8; ++fw) {  // tmp2[j][w'] = k_j . pos_q[r2min+w']
      f32x4 t = (f32x4){0.f, 0.f, 0.f, 0.f};
      const s16x8 p0 = *(const s16x8*)&PQs[(fw * 16 + lr) * 64 + lg * 8];
      const s16x8 p1 = *(const s16x8*)&PQs[(fw * 16 + lr) * 64 + 32 + lg * 8];
      t = MFMA16(ka0, p0, t);
      t = MFMA16(ka1, p1, t);
#pragma unroll
      for (int r = 0; r < 4; ++r) TQ[(band + lg * 4 + r) * 128 + fw * 16 + lr] = t[r];
    }
    __syncthreads();

    // ---- Phase C: gather + mask + online softmax
    float pv[4][4];
#pragma unroll
    for (int fj = 0; fj < 4; ++fj) {
      const int jl = fj * 16 + lr;
      const int jg = j0 + jl;
      const bool ok = msk[jl] != 0;
#pragma unroll
      for (int r = 0; r < 4; ++r) {
        const int il = band + lg * 4 + r;
        const int ig = i0 + il;
        const int delta = ig - jg;
        const int w = imin(imax(delta + 512, 0), 1023) - rmin;
        const int w2 = imin(imax(-delta + 512, 0), 1023) - r2min;
        const float s = (sacc[fj][r] + TK[il * 128 + w] + TQ[jl * 128 + w2]) * ATT_SCALE;
        pv[fj][r] = ok ? s : -1e9f;
      }
    }
#pragma unroll
    for (int r = 0; r < 4; ++r) {
      float m = fmaxf(fmaxf(pv[0][r], pv[1][r]), fmaxf(pv[2][r], pv[3][r]));
#pragma unroll
      for (int dd = 1; dd < 16; dd <<= 1) m = fmaxf(m, __shfl_xor(m, dd, 64));
      const float mnew = fmaxf(mprev[r], m);
      const float corr = __expf(mprev[r] - mnew);
      float rs = 0.f;
#pragma unroll
      for (int fj = 0; fj < 4; ++fj) { pv[fj][r] = __expf(pv[fj][r] - mnew); rs += pv[fj][r]; }
#pragma unroll
      for (int dd = 1; dd < 16; dd <<= 1) rs += __shfl_xor(rs, dd, 64);
      lsum[r] = lsum[r] * corr + rs;
      mprev[r] = mnew;
#pragma unroll
      for (int fd = 0; fd < 4; ++fd) oacc[fd][r] *= corr;
    }
#pragma unroll
    for (int fj = 0; fj < 4; ++fj)
#pragma unroll
      for (int r = 0; r < 4; ++r)
        Ps[(band + lg * 4 + r) * 64 + fj * 16 + lr] = f2bf(pv[fj][r]);
    __syncthreads();

    // ---- Phase D: PV
    const s16x8 pa0 = *(const s16x8*)&Ps[(band + lr) * 64 + lg * 8];
    const s16x8 pa1 = *(const s16x8*)&Ps[(band + lr) * 64 + 32 + lg * 8];
#pragma unroll
    for (int fd = 0; fd < 4; ++fd) {
      const s16x8 v0 = *(const s16x8*)&Vs[(fd * 16 + lr) * 64 + lg * 8];
      const s16x8 v1 = *(const s16x8*)&Vs[(fd * 16 + lr) * 64 + 32 + lg * 8];
      oacc[fd] = MFMA16(pa0, v0, oacc[fd]);
      oacc[fd] = MFMA16(pa1, v1, oacc[fd]);
    }
    __syncthreads();
  }

  // epilogue: divide by l, write [B,S,HID] bf16
#pragma unroll
  for (int fd = 0; fd < 4; ++fd) {
    const int d = h * DH + fd * 16 + lr;
#pragma unroll
    for (int r = 0; r < 4; ++r) {
      const int ig = i0 + band + lg * 4 + r;
      ao[((size_t)b * SS + ig) * HIDN + d] = f2bf(oacc[fd][r] / lsum[r]);
    }
  }
}

// ---------------------------------------------------------------- launch
extern "C" void kernel_launch(void* const* d_in, const int* in_sizes, int n_in,
                              void* d_out, int out_size, void* d_ws, size_t ws_size,
                              hipStream_t stream) {
  const float* x   = (const float*)d_in[0];
  const int* mask  = (const int*)d_in[1];
  const float* Wq  = (const float*)d_in[2];  const float* bq  = (const float*)d_in[3];
  const float* Wk  = (const float*)d_in[4];  const float* bk  = (const float*)d_in[5];
  const float* Wv  = (const float*)d_in[6];  const float* bv  = (const float*)d_in[7];
  const float* Wo  = (const float*)d_in[8];  const float* bo  = (const float*)d_in[9];
  const float* rel = (const float*)d_in[10];
  const float* Wpk = (const float*)d_in[11]; const float* bpk = (const float*)d_in[12];
  const float* Wpq = (const float*)d_in[13]; const float* bpq = (const float*)d_in[14];
  const float* g1  = (const float*)d_in[15]; const float* be1 = (const float*)d_in[16];
  const float* g2  = (const float*)d_in[17]; const float* be2 = (const float*)d_in[18];
  const float* W1  = (const float*)d_in[19]; const float* bf1 = (const float*)d_in[20];
  const float* W2  = (const float*)d_in[21]; const float* bf2 = (const float*)d_in[22];
  float* out = (float*)d_out;

  char* ws = (char*)d_ws;
  size_t off = 0;
  auto carve = [&](size_t bytes) { char* p = ws + off; off += (bytes + 255) & ~(size_t)255; return p; };
  const size_t MB8 = (size_t)4096 * 1024 * 2;
  short* xn    = (short*)carve(MB8);
  short* qhB   = (short*)carve(MB8);
  short* khB   = (short*)carve(MB8);
  short* vTB   = (short*)carve(MB8);
  short* aoB   = (short*)carve(MB8);
  short* hnB   = (short*)carve(MB8);
  short* midB  = (short*)carve((size_t)4096 * 4096 * 2);
  short* poskB = (short*)carve((size_t)1024 * 1024 * 2);
  short* posqB = (short*)carve((size_t)1024 * 1024 * 2);
  short* WqT   = (short*)carve((size_t)1024 * 1024 * 2);
  short* WkT   = (short*)carve((size_t)1024 * 1024 * 2);
  short* WvT   = (short*)carve((size_t)1024 * 1024 * 2);
  short* WoT   = (short*)carve((size_t)1024 * 1024 * 2);
  short* WpkT  = (short*)carve((size_t)1024 * 1024 * 2);
  short* WpqT  = (short*)carve((size_t)1024 * 1024 * 2);
  short* W1T   = (short*)carve((size_t)4096 * 1024 * 2);
  short* W2T   = (short*)carve((size_t)4096 * 1024 * 2);
  short* relbf = (short*)carve((size_t)1024 * 1024 * 2);
  (void)ws_size; (void)in_sizes; (void)n_in; (void)out_size;

  const int M = BB * SS;  // 4096

  // weight prep
  k_tcast<<<dim3(32, 32), 256, 0, stream>>>(Wq, WqT, 1024, 1024);
  k_tcast<<<dim3(32, 32), 256, 0, stream>>>(Wk, WkT, 1024, 1024);
  k_tcast<<<dim3(32, 32), 256, 0, stream>>>(Wv, WvT, 1024, 1024);
  k_tcast<<<dim3(32, 32), 256, 0, stream>>>(Wo, WoT, 1024, 1024);
  k_tcast<<<dim3(32, 32), 256, 0, stream>>>(Wpk, WpkT, 1024, 1024);
  k_tcast<<<dim3(32, 32), 256, 0, stream>>>(Wpq, WpqT, 1024, 1024);
  k_tcast<<<dim3(128, 32), 256, 0, stream>>>(W1, W1T, 1024, 4096);
  k_tcast<<<dim3(32, 128), 256, 0, stream>>>(W2, W2T, 4096, 1024);
  k_cast<<<1024, 256, 0, stream>>>(rel, relbf, 1024 * 1024 / 4);

  // sublayer 1
  k_ln<<<M, 256, 0, stream>>>(x, g1, be1, xn);
  k_gemm<OM_HEADS><<<dim3(8, 32), 256, 0, stream>>>(xn, WqT, bq, nullptr, qhB, M, 1024, 1024);
  k_gemm<OM_HEADS><<<dim3(8, 32), 256, 0, stream>>>(xn, WkT, bk, nullptr, khB, M, 1024, 1024);
  k_gemm<OM_VT><<<dim3(8, 32), 256, 0, stream>>>(xn, WvT, bv, nullptr, vTB, M, 1024, 1024);
  k_gemm<OM_POS><<<dim3(8, 8), 256, 0, stream>>>(relbf, WpkT, bpk, nullptr, poskB, 1024, 1024, 1024);
  k_gemm<OM_POS><<<dim3(8, 8), 256, 0, stream>>>(relbf, WpqT, bpq, nullptr, posqB, 1024, 1024, 1024);
  k_attn<<<1024, 256, 0, stream>>>(qhB, khB, vTB, poskB, posqB, mask, aoB);
  k_gemm<OM_RESID><<<dim3(8, 32), 256, 0, stream>>>(aoB, WoT, bo, x, out, M, 1024, 1024);

  // sublayer 2
  k_ln<<<M, 256, 0, stream>>>(out, g2, be2, hnB);
  k_gemm<OM_GELU><<<dim3(32, 32), 256, 0, stream>>>(hnB, W1T, bf1, nullptr, midB, M, 4096, 1024);
  k_gemm<OM_RESID><<<dim3(8, 32), 256, 0, stream>>>(midB, W2T, bf2, out, out, M, 1024, 4096);
}